// Round 13
// baseline (201.140 us; speedup 1.0000x reference)
//
#include <hip/hip_runtime.h>
#include <hip/hip_bf16.h>
#include <hip/hip_fp16.h>

// GCN forward: emb-gather -> GCNConv(64->128) -> ReLU -> GCNConv(128->128) -> ReLU
//              -> global_max_pool -> Linear(128->10)
// N=100000, E=600000, VOCAB=5000, G=2000, C=10.
// Layer-1 agg in 64-dim embedding space (linearity) -> gemm1 -> h1 fp16.
// Layer-2: aggregate in h1-space (linearity: z = (di*(di*h1_i + sum dj*h1_j))@W2 + b2),
// fused gather + MFMA(W2) + relu + max-pool in ONE kernel. P is never materialized.

typedef _Float16 h8 __attribute__((ext_vector_type(8)));
typedef float f32x4 __attribute__((ext_vector_type(4)));

// Zero deg, pool, Xagg pad rows.
__global__ __launch_bounds__(256) void k_zero(int4* __restrict__ deg4, int n4i,
                                              int4* __restrict__ pool4, int p4i,
                                              int4* __restrict__ xpad, int x4i) {
    int t = blockIdx.x * 256 + threadIdx.x;
    int4 z = make_int4(0, 0, 0, 0);
    if (t < n4i) deg4[t] = z;
    if (t < p4i) pool4[t] = z;
    if (t < x4i) xpad[t] = z;
}

// Fused: [0,gE) degree atomics; [gE,gE+nCast) e16 = fp16(emb); then W1T; then W2T.
__global__ __launch_bounds__(256) void k_degprep(const int* __restrict__ dst, int* __restrict__ deg, int E,
                                                 const float* __restrict__ emb, __half2* __restrict__ e16,
                                                 const float* __restrict__ W1, _Float16* __restrict__ W1T,
                                                 const float* __restrict__ W2, _Float16* __restrict__ W2T,
                                                 int nEmbF, int gE, int nCast) {
    int bid = blockIdx.x;
    if (bid < gE) {
        int e = bid * 256 + threadIdx.x;
        if (e < E) atomicAdd(&deg[dst[e]], 1);
    } else if (bid < gE + nCast) {
        int t = (bid - gE) * 256 + threadIdx.x;  // one thread = 4 floats
        if (t * 4 < nEmbF) {
            float4 v = *(const float4*)&emb[t * 4];
            e16[t * 2] = __floats2half2_rn(v.x, v.y);
            e16[t * 2 + 1] = __floats2half2_rn(v.z, v.w);
        }
    } else if (bid < gE + nCast + 32) {
        int t = (bid - gE - nCast) * 256 + threadIdx.x;  // 128*64
        int c = t >> 6, k = t & 63;
        W1T[c * 64 + k] = (_Float16)W1[k * 128 + c];
    } else {
        int t = (bid - gE - nCast - 32) * 256 + threadIdx.x;  // 128*128
        if (t < 128 * 128) {
            int c = t >> 7, k = t & 127;
            W2T[c * 128 + k] = (_Float16)W2[k * 128 + c];
        }
    }
}

// scan1 + dinv fused
__global__ __launch_bounds__(256) void k_scan1(const int* __restrict__ deg, int* __restrict__ exc,
                                               int* __restrict__ bsums, float* __restrict__ dinv, int N) {
    __shared__ int s[256];
    int i = blockIdx.x * 256 + threadIdx.x;
    int v = (i < N) ? deg[i] : 0;
    if (i < N) dinv[i] = rsqrtf((float)(v + 1));  // +1 self-loop
    s[threadIdx.x] = v;
    __syncthreads();
    for (int off = 1; off < 256; off <<= 1) {
        int t = (threadIdx.x >= (unsigned)off) ? s[threadIdx.x - off] : 0;
        __syncthreads();
        s[threadIdx.x] += t;
        __syncthreads();
    }
    if (i < N) exc[i] = s[threadIdx.x] - v;
    if (threadIdx.x == 255) bsums[blockIdx.x] = s[255];
}

__global__ __launch_bounds__(512) void k_scan2(int* __restrict__ bsums, int nb) {
    __shared__ int s[512];
    int i = threadIdx.x;
    int v = (i < nb) ? bsums[i] : 0;
    s[i] = v;
    __syncthreads();
    for (int off = 1; off < 512; off <<= 1) {
        int t = (i >= off) ? s[i - off] : 0;
        __syncthreads();
        s[i] += t;
        __syncthreads();
    }
    if (i < nb) bsums[i] = s[i] - v;
}

__global__ __launch_bounds__(256) void k_scan3(int* __restrict__ rowstart, int* __restrict__ cursor,
                                               const int* __restrict__ bsums, int N, int E) {
    int i = blockIdx.x * 256 + threadIdx.x;
    if (i < N) {
        int r = rowstart[i] + bsums[blockIdx.x];
        rowstart[i] = r;
        cursor[i] = r;
    }
    if (i == 0 && blockIdx.x == 0) rowstart[N] = E;
}

// CSR fill: rec[pos] = {x[src], dinv[src] bits, src, 0} — ONE 16B scattered store.
__global__ __launch_bounds__(256) void k_fill(const int* __restrict__ src, const int* __restrict__ dst,
                                              const int* __restrict__ x, const float* __restrict__ dinv,
                                              int* __restrict__ cursor, int4* __restrict__ rec, int E) {
    int e = blockIdx.x * 256 + threadIdx.x;
    if (e < E) {
        int d = dst[e];
        int s = src[e];
        int pos = atomicAdd(&cursor[d], 1);
        rec[pos] = make_int4(x[s], __float_as_int(dinv[s]), s, 0);
    }
}

// 64-dim embedding-space aggregation: Xagg[i] = di*(di*e16[x_i] + sum dj*e16[x_j]).
// 256 thr = 8 half-waves x 2 nodes; dual 8-deep clamped gather batches.
__global__ __launch_bounds__(256) void k_agge(const __half2* __restrict__ e16, const int* __restrict__ x,
                                              const float* __restrict__ dinv, const int* __restrict__ rs,
                                              const int4* __restrict__ rec, __half2* __restrict__ Xagg, int N) {
    int lane = threadIdx.x & 31;
    int n0 = (blockIdx.x * 8 + (threadIdx.x >> 5)) * 2;
    if (n0 >= N) return;
    int nB = (n0 + 1 < N) ? n0 + 1 : n0;
    int cA0 = rs[n0], cA1 = rs[n0 + 1];
    int cB0 = rs[nB], cB1 = rs[nB + 1];
    bool hasA = cA0 < cA1, hasB = cB0 < cB1;
    __half2 tA[8], tB[8];
    float wA[8], wB[8];
#pragma unroll
    for (int i = 0; i < 8; ++i) {
        int ei = cA0 + i;
        int ec = (ei < cA1) ? ei : (hasA ? cA1 - 1 : 0);
        int4 r2 = rec[ec];
        tA[i] = e16[(size_t)r2.x * 32 + lane];
        wA[i] = (ei < cA1) ? __int_as_float(r2.y) : 0.f;
    }
#pragma unroll
    for (int i = 0; i < 8; ++i) {
        int ei = cB0 + i;
        int ec = (ei < cB1) ? ei : (hasB ? cB1 - 1 : 0);
        int4 r2 = rec[ec];
        tB[i] = e16[(size_t)r2.x * 32 + lane];
        wB[i] = (ei < cB1) ? __int_as_float(r2.y) : 0.f;
    }
    float dA = dinv[n0], dB = dinv[nB];
    float2 sA = __half22float2(e16[(size_t)x[n0] * 32 + lane]);
    float2 sB = __half22float2(e16[(size_t)x[nB] * 32 + lane]);
    float aA0 = dA * sA.x, aA1 = dA * sA.y;
    float aB0 = dB * sB.x, aB1 = dB * sB.y;
#pragma unroll
    for (int i = 0; i < 8; ++i) {
        float2 tf = __half22float2(tA[i]);
        aA0 = fmaf(wA[i], tf.x, aA0);
        aA1 = fmaf(wA[i], tf.y, aA1);
    }
#pragma unroll
    for (int i = 0; i < 8; ++i) {
        float2 tf = __half22float2(tB[i]);
        aB0 = fmaf(wB[i], tf.x, aB0);
        aB1 = fmaf(wB[i], tf.y, aB1);
    }
    for (int e = cA0 + 8; e < cA1; e += 8) {
#pragma unroll
        for (int i = 0; i < 8; ++i) {
            int ei = e + i;
            int ec = (ei < cA1) ? ei : cA1 - 1;
            int4 r2 = rec[ec];
            tA[i] = e16[(size_t)r2.x * 32 + lane];
            wA[i] = (ei < cA1) ? __int_as_float(r2.y) : 0.f;
        }
#pragma unroll
        for (int i = 0; i < 8; ++i) {
            float2 tf = __half22float2(tA[i]);
            aA0 = fmaf(wA[i], tf.x, aA0);
            aA1 = fmaf(wA[i], tf.y, aA1);
        }
    }
    for (int e = cB0 + 8; e < cB1; e += 8) {
#pragma unroll
        for (int i = 0; i < 8; ++i) {
            int ei = e + i;
            int ec = (ei < cB1) ? ei : cB1 - 1;
            int4 r2 = rec[ec];
            tB[i] = e16[(size_t)r2.x * 32 + lane];
            wB[i] = (ei < cB1) ? __int_as_float(r2.y) : 0.f;
        }
#pragma unroll
        for (int i = 0; i < 8; ++i) {
            float2 tf = __half22float2(tB[i]);
            aB0 = fmaf(wB[i], tf.x, aB0);
            aB1 = fmaf(wB[i], tf.y, aB1);
        }
    }
    Xagg[(size_t)n0 * 32 + lane] = __floats2half2_rn(dA * aA0, dA * aA1);
    Xagg[(size_t)nB * 32 + lane] = __floats2half2_rn(dB * aB0, dB * aB1);
}

// h1 = relu(Xagg @ W1 + b1). 256 thr = 4 waves x 16 rows, block = 64 rows.
// Stores vectorized via LDS restage (4x16B per thread, coalesced).
__global__ __launch_bounds__(256) void k_gemm1(const _Float16* __restrict__ Xagg,
                                               const _Float16* __restrict__ W1T,
                                               const float* __restrict__ b1,
                                               _Float16* __restrict__ h1, int Npad) {
    __shared__ _Float16 Hs[64][136];
    int tid = threadIdx.x;
    int l = tid & 63, wid = tid >> 6;
    int r = l & 15, kg = l >> 4;
    int blk0 = blockIdx.x * 64;
    f32x4 acc[8];
#pragma unroll
    for (int ct = 0; ct < 8; ++ct) acc[ct] = (f32x4){0.f, 0.f, 0.f, 0.f};
    const _Float16* ab = Xagg + (size_t)(blk0 + wid * 16 + r) * 64 + kg * 8;
#pragma unroll
    for (int kc = 0; kc < 2; ++kc) {
        h8 a = *(const h8*)(ab + kc * 32);
#pragma unroll
        for (int ct = 0; ct < 8; ++ct) {
            h8 b = *(const h8*)(W1T + (size_t)(ct * 16 + r) * 64 + kc * 32 + kg * 8);
            acc[ct] = __builtin_amdgcn_mfma_f32_16x16x32_f16(a, b, acc[ct], 0, 0, 0);
        }
    }
#pragma unroll
    for (int ct = 0; ct < 8; ++ct) {
        float bias = b1[ct * 16 + r];
#pragma unroll
        for (int i = 0; i < 4; ++i)
            Hs[wid * 16 + 4 * kg + i][ct * 16 + r] = (_Float16)fmaxf(acc[ct][i] + bias, 0.f);
    }
    __syncthreads();
    int row = tid >> 2, q = tid & 3;
    const int4* srcp = (const int4*)&Hs[row][q * 32];
    int4 v0 = srcp[0], v1 = srcp[1], v2 = srcp[2], v3 = srcp[3];
    int4* dst = (int4*)(h1 + (size_t)(blk0 + row) * 128 + q * 32);
    dst[0] = v0; dst[1] = v1; dst[2] = v2; dst[3] = v3;
}

// Fused layer-2 aggregation + W2 GEMM + relu + global_max_pool. 256 thr = 4 waves x 16 nodes.
// Per wave: lanes (r,kg) aggregate Y[r] = di*(di*h1_r + sum_j dj*h1_j) in f32 (4 h8 frags),
// edge loop runs to wave-max degree (clamped, weight-0 masked). Then 32 MFMA vs W2T,
// +b2, relu, max-pool via LDS slots (block = 64 sorted nodes -> <=8 graphs) + global atomics.
#define SLOTS 8
__global__ __launch_bounds__(256) void k_aggpool(const _Float16* __restrict__ h1,
                                                 const int* __restrict__ batch,
                                                 const float* __restrict__ dinv,
                                                 const int* __restrict__ rs,
                                                 const int4* __restrict__ rec,
                                                 const _Float16* __restrict__ W2T,
                                                 const float* __restrict__ b2,
                                                 float* __restrict__ pool, int N) {
    __shared__ int lpool[SLOTS][128];
    int tid = threadIdx.x;
    for (int i = tid; i < SLOTS * 128; i += 256) ((int*)lpool)[i] = 0;
    __syncthreads();
    int l = tid & 63, wid = tid >> 6;
    int r = l & 15, kg = l >> 4;
    int blk0 = blockIdx.x * 64;
    int gfirst = batch[blk0 < N ? blk0 : N - 1];
    int base = blk0 + wid * 16;
    int noder = base + r;
    if (noder >= N) noder = N - 1;
    int e = rs[noder], e1 = rs[noder + 1];
    float di = dinv[noder];
    float y[32];
    {
        const _Float16* sp = h1 + (size_t)noder * 128 + kg * 8;
        // self term: init with di*h1_i; final *di gives di^2*h1_i (z = di*(di*h1_i + sum))
        // BUG FIX (round 12): was di*di here -> di^3 self term after the final *di.
#pragma unroll
        for (int kc = 0; kc < 4; ++kc) {
            h8 s = *(const h8*)(sp + kc * 32);
#pragma unroll
            for (int j = 0; j < 8; ++j) y[kc * 8 + j] = di * (float)s[j];
        }
    }
    // edge loop: 2-wide, runs to wave-max degree; inactive lanes read rec[0] with w=0
    while (__any(e < e1)) {
        int ec0 = (e < e1) ? e : 0;
        int4 r0 = rec[ec0];
        float w0 = (e < e1) ? __int_as_float(r0.y) : 0.f;
        int ec1 = (e + 1 < e1) ? e + 1 : 0;
        int4 r1 = rec[ec1];
        float w1 = (e + 1 < e1) ? __int_as_float(r1.y) : 0.f;
        const _Float16* p0 = h1 + (size_t)r0.z * 128 + kg * 8;
        const _Float16* p1 = h1 + (size_t)r1.z * 128 + kg * 8;
#pragma unroll
        for (int kc = 0; kc < 4; ++kc) {
            h8 t0 = *(const h8*)(p0 + kc * 32);
            h8 t1 = *(const h8*)(p1 + kc * 32);
#pragma unroll
            for (int j = 0; j < 8; ++j)
                y[kc * 8 + j] = fmaf(w1, (float)t1[j], fmaf(w0, (float)t0[j], y[kc * 8 + j]));
        }
        e += 2;
    }
    // Y *= di, convert to fp16 A-fragments
    h8 af[4];
#pragma unroll
    for (int kc = 0; kc < 4; ++kc)
#pragma unroll
        for (int j = 0; j < 8; ++j) af[kc][j] = (_Float16)(di * y[kc * 8 + j]);
    // z = Y @ W2
    f32x4 acc[8];
#pragma unroll
    for (int ct = 0; ct < 8; ++ct) acc[ct] = (f32x4){0.f, 0.f, 0.f, 0.f};
#pragma unroll
    for (int kc = 0; kc < 4; ++kc) {
#pragma unroll
        for (int ct = 0; ct < 8; ++ct) {
            h8 b = *(const h8*)(W2T + (size_t)(ct * 16 + r) * 128 + kc * 32 + kg * 8);
            acc[ct] = __builtin_amdgcn_mfma_f32_16x16x32_f16(af[kc], b, acc[ct], 0, 0, 0);
        }
    }
    // bias + relu + pool (output rows of MFMA are 4*kg+i, cols ct*16+r)
    int gs[4];
#pragma unroll
    for (int i = 0; i < 4; ++i) {
        int nd = base + 4 * kg + i;
        gs[i] = (nd < N) ? batch[nd] : -1;
    }
#pragma unroll
    for (int ct = 0; ct < 8; ++ct) {
        float bias = b2[ct * 16 + r];
#pragma unroll
        for (int i = 0; i < 4; ++i) {
            if (gs[i] >= 0) {
                float z = acc[ct][i] + bias;
                if (z > 0.f) {
                    int slot = gs[i] - gfirst;
                    int col = ct * 16 + r;
                    if (slot < SLOTS)
                        atomicMax(&lpool[slot][col], __float_as_int(z));
                    else
                        atomicMax((int*)&pool[(size_t)gs[i] * 128 + col], __float_as_int(z));
                }
            }
        }
    }
    __syncthreads();
    for (int i = tid; i < SLOTS * 128; i += 256) {
        int v = ((int*)lpool)[i];
        if (v > 0) atomicMax((int*)&pool[(size_t)(gfirst + (i >> 7)) * 128 + (i & 127)], v);
    }
}

// out[g][c] = blin[c] + sum_f pool[g][f] * Wlin[f][c]
__global__ __launch_bounds__(256) void k_final(const float* __restrict__ pool, const float* __restrict__ Wlin,
                                               const float* __restrict__ blin, float* __restrict__ out, int G) {
    int t = blockIdx.x * 256 + threadIdx.x;
    if (t >= G * 10) return;
    int g = t / 10, c = t % 10;
    float acc = blin[c];
    const float* pr = pool + (size_t)g * 128;
#pragma unroll 8
    for (int f = 0; f < 128; ++f) acc = fmaf(pr[f], Wlin[f * 10 + c], acc);
    out[t] = acc;
}

extern "C" void kernel_launch(void* const* d_in, const int* in_sizes, int n_in,
                              void* d_out, int out_size, void* d_ws, size_t ws_size,
                              hipStream_t stream) {
    const int* x = (const int*)d_in[0];
    const int* ei = (const int*)d_in[1];
    const int* batch = (const int*)d_in[2];
    const float* emb = (const float*)d_in[4];
    const float* W1 = (const float*)d_in[5];
    const float* b1 = (const float*)d_in[6];
    const float* W2 = (const float*)d_in[7];
    const float* b2 = (const float*)d_in[8];
    const float* Wlin = (const float*)d_in[9];
    const float* blin = (const float*)d_in[10];
    float* out = (float*)d_out;

    int N = in_sizes[0];
    int E = in_sizes[1] / 2;
    int VOCAB = in_sizes[4] / 64;
    int G = out_size / 10;
    const int* srcp = ei;
    const int* dstp = ei + E;

    char* p = (char*)d_ws;
    auto alloc = [&](size_t bytes) -> char* {
        char* r = p;
        p += (bytes + 255) & ~(size_t)255;
        return r;
    };
    int Npad = (N + 63) & ~63;
    int* deg = (int*)alloc((size_t)N * 4);
    int* cursor = (int*)alloc((size_t)N * 4);
    int* rowstart = (int*)alloc((size_t)(N + 1) * 4);
    int* bsums = (int*)alloc(512 * 4);
    float* dinv = (float*)alloc((size_t)N * 4);
    int4* rec = (int4*)alloc((size_t)E * 16);
    _Float16* e16 = (_Float16*)alloc((size_t)VOCAB * 64 * 2);
    _Float16* W1T = (_Float16*)alloc(128 * 64 * 2);
    _Float16* W2T = (_Float16*)alloc(128 * 128 * 2);
    _Float16* Xagg = (_Float16*)alloc((size_t)Npad * 64 * 2);
    _Float16* h1 = (_Float16*)alloc((size_t)Npad * 128 * 2);
    float* pool = (float*)alloc((size_t)G * 128 * 4);

    int gE = (E + 255) / 256;
    int gN = (N + 255) / 256;  // 391 <= 512 (scan2 capacity)
    int nEmbF = VOCAB * 64;
    int nCast = (nEmbF / 4 + 255) / 256;

    int n4i = N / 4, p4i = G * 128 / 4;
    int x4i = (Npad - N) * 64 * 2 / 16;  // Xagg pad rows in int4s
    int zmax = n4i > p4i ? n4i : p4i;
    k_zero<<<(zmax + 255) / 256, 256, 0, stream>>>((int4*)deg, n4i, (int4*)pool, p4i,
                                                   (int4*)(Xagg + (size_t)N * 64), x4i);
    k_degprep<<<gE + nCast + 32 + 64, 256, 0, stream>>>(dstp, deg, E, emb, (__half2*)e16, W1, W1T,
                                                        W2, W2T, nEmbF, gE, nCast);
    k_scan1<<<gN, 256, 0, stream>>>(deg, rowstart, bsums, dinv, N);
    k_scan2<<<1, 512, 0, stream>>>(bsums, gN);
    k_scan3<<<gN, 256, 0, stream>>>(rowstart, cursor, bsums, N, E);
    k_fill<<<gE, 256, 0, stream>>>(srcp, dstp, x, dinv, cursor, rec, E);
    k_agge<<<(N + 15) / 16, 256, 0, stream>>>((const __half2*)e16, x, dinv, rowstart, rec,
                                              (__half2*)Xagg, N);
    k_gemm1<<<Npad / 64, 256, 0, stream>>>(Xagg, W1T, b1, h1, Npad);
    k_aggpool<<<(N + 63) / 64, 256, 0, stream>>>(h1, batch, dinv, rowstart, rec, W2T, b2, pool, N);
    k_final<<<(G * 10 + 255) / 256, 256, 0, stream>>>(pool, Wlin, blin, out, G);
}